// Round 9
// baseline (273.725 us; speedup 1.0000x reference)
//
#include <hip/hip_runtime.h>
#include <hip/hip_bf16.h>
#include <math.h>

#define B_   2
#define D_   5
#define H_   32
#define W_   32
#define C_   256
#define NH_  8
#define NL_  5
#define NP_  16
#define HD_  32
#define HW_  1024
#define LQ_  5120            // D*H*W
#define M_   (B_*LQ_)        // 10240 rows
#define MLP_ 1024
#define NCAT 2176            // GEMM N: 256 val + 1280 off + 640 logits
#define NQ2  1920            // compact qkv2 row: 1280 off + 640 logits

typedef unsigned short u16;
typedef __bf16 bf16x8 __attribute__((ext_vector_type(8)));
typedef float  f32x4  __attribute__((ext_vector_type(4)));

__device__ __forceinline__ float b2f(u16 v) {
    union { float f; unsigned u; } x; x.u = ((unsigned)v) << 16; return x.f;
}
__device__ __forceinline__ u16 f2b(float f) {
    union { float f; unsigned u; } x; x.f = f;
    unsigned r = x.u + 0x7fffu + ((x.u >> 16) & 1u);
    return (u16)(r >> 16);
}
__device__ __forceinline__ void gload16(const u16* g, u16* l) {
    __builtin_amdgcn_global_load_lds(
        (const __attribute__((address_space(1))) unsigned int*)g,
        (__attribute__((address_space(3))) unsigned int*)l, 16, 0, 0);
}

// ------------- weight prep + LN3 fused in ONE dispatch ----------------------
#define SEG0 557056
#define SEG1 622592
#define SEG2 884736
#define SEG3 1146880
#define SEGT 1149056
#define PREP_BLKS ((SEGT + 255) / 256)
__global__ void prep_and_ln3(const float* __restrict__ w_val, const float* __restrict__ w_off,
                             const float* __restrict__ w_attn, const float* __restrict__ w_out,
                             const float* __restrict__ w_fc1, const float* __restrict__ w_fc2,
                             const float* __restrict__ b_val, const float* __restrict__ b_off,
                             const float* __restrict__ b_attn,
                             u16* __restrict__ wcatT, u16* __restrict__ woutT,
                             u16* __restrict__ wfc1T, u16* __restrict__ wfc2T,
                             float* __restrict__ biascat,
                             const float* __restrict__ x, const float* __restrict__ g3,
                             const float* __restrict__ b3, u16* __restrict__ qbuf) {
    if (blockIdx.x >= PREP_BLKS) {
        // ---- LN3: one wave per row, 4 rows/block ----
        int wave = threadIdx.x >> 6, lane = threadIdx.x & 63;
        int row = (blockIdx.x - PREP_BLKS) * 4 + wave;
        const float4 v = *(const float4*)(x + (size_t)row * C_ + lane * 4);
        float s = v.x + v.y + v.z + v.w;
#pragma unroll
        for (int o = 1; o < 64; o <<= 1) s += __shfl_xor(s, o, 64);
        float mean = s * (1.0f / C_);
        float4 d = { v.x - mean, v.y - mean, v.z - mean, v.w - mean };
        float s2 = d.x * d.x + d.y * d.y + d.z * d.z + d.w * d.w;
#pragma unroll
        for (int o = 1; o < 64; o <<= 1) s2 += __shfl_xor(s2, o, 64);
        float r = rsqrtf(s2 * (1.0f / C_) + 1e-5f);
        const float4 gg = *(const float4*)(g3 + lane * 4);
        const float4 bb = *(const float4*)(b3 + lane * 4);
        unsigned lo = (unsigned)f2b(d.x * r * gg.x + bb.x) |
                      ((unsigned)f2b(d.y * r * gg.y + bb.y) << 16);
        unsigned hi = (unsigned)f2b(d.z * r * gg.z + bb.z) |
                      ((unsigned)f2b(d.w * r * gg.w + bb.w) << 16);
        uint2 pk = { lo, hi };
        *(uint2*)(qbuf + (size_t)row * C_ + lane * 4) = pk;
        return;
    }
    int idx = blockIdx.x * blockDim.x + threadIdx.x;
    if (idx < SEG0) {
        int n = idx >> 8, k = idx & 255;
        float v;
        if (n < 256)        v = w_val[k * 256 + n];
        else if (n < 1536)  v = w_off[k * 1280 + (n - 256)];
        else                v = w_attn[k * 640 + (n - 1536)];
        wcatT[idx] = f2b(v);
    } else if (idx < SEG1) {
        int i = idx - SEG0; int n = i >> 8, k = i & 255;
        woutT[i] = f2b(w_out[k * 256 + n]);
    } else if (idx < SEG2) {
        int i = idx - SEG1; int n = i >> 8, k = i & 255;
        wfc1T[i] = f2b(w_fc1[k * 1024 + n]);
    } else if (idx < SEG3) {
        int i = idx - SEG2; int n = i >> 10, k = i & 1023;
        wfc2T[i] = f2b(w_fc2[k * 256 + n]);
    } else if (idx < SEGT) {
        int t = idx - SEG3;
        float v;
        if (t < 256)        v = b_val[t];
        else if (t < 1536)  v = b_off[t - 256];
        else                v = b_attn[t - 1536];
        biascat[t] = v;
    }
}

// ------------- bf16 MFMA GEMM, 128x128 tile, BK=64, global_load_lds ---------
// mode 0: qkv split — col<256 scatter to valT[b][h][pix][32], else qkv2[M][1920]
// mode 1: out bf16 = gelu_exact(v)
#define BK 64
__launch_bounds__(256, 2)
__global__ void gemm128(const u16* __restrict__ A, const u16* __restrict__ Bt,
                        const float* __restrict__ bias,
                        u16* __restrict__ out, u16* __restrict__ valT,
                        int Mdim, int Ndim, int Kdim,
                        int mode, int nTiles) {
    __shared__ __align__(16) u16 lsA[128 * BK];
    __shared__ __align__(16) u16 lsB[128 * BK];
    int bm = blockIdx.x / nTiles, bn = blockIdx.x % nTiles;
    int m0 = bm * 128, n0 = bn * 128;
    int tid = threadIdx.x;
    int lane = tid & 63, wv = tid >> 6;
    int quad = lane >> 4, l16 = lane & 15;
    int rw = (wv >> 1) * 64, cw = (wv & 1) * 64;

    f32x4 acc[4][4];
#pragma unroll
    for (int i = 0; i < 4; i++)
#pragma unroll
        for (int j = 0; j < 4; j++) { f32x4 z = {0.f, 0.f, 0.f, 0.f}; acc[i][j] = z; }

    for (int k0 = 0; k0 < Kdim; k0 += BK) {
        __syncthreads();
#pragma unroll
        for (int s = 0; s < 4; s++) {
            int cc = s * 256 + wv * 64 + lane;
            int row = cc >> 3, kc = (cc & 7) << 3;
            int lbase = (s * 256 + wv * 64) * 8;   // u16 units, wave-uniform
            gload16(A  + (size_t)(m0 + row) * Kdim + k0 + kc, &lsA[lbase]);
            gload16(Bt + (size_t)(n0 + row) * Kdim + k0 + kc, &lsB[lbase]);
        }
        __syncthreads();
#pragma unroll
        for (int kk = 0; kk < 2; kk++) {
            bf16x8 af[4], bfr[4];
#pragma unroll
            for (int i = 0; i < 4; i++)
                af[i] = *(const bf16x8*)(&lsA[(rw + i * 16 + l16) * BK + kk * 32 + quad * 8]);
#pragma unroll
            for (int j = 0; j < 4; j++)
                bfr[j] = *(const bf16x8*)(&lsB[(cw + j * 16 + l16) * BK + kk * 32 + quad * 8]);
#pragma unroll
            for (int i = 0; i < 4; i++)
#pragma unroll
                for (int j = 0; j < 4; j++)
                    acc[i][j] = __builtin_amdgcn_mfma_f32_16x16x32_bf16(
                        af[i], bfr[j], acc[i][j], 0, 0, 0);
        }
    }

#pragma unroll
    for (int i = 0; i < 4; i++) {
#pragma unroll
        for (int j = 0; j < 4; j++) {
            int col = n0 + cw + j * 16 + l16;
            float bb = bias[col];
#pragma unroll
            for (int r = 0; r < 4; r++) {
                int row = m0 + rw + i * 16 + quad * 4 + r;
                float v = acc[i][j][r] + bb;
                if (mode == 0) {
                    if (col < 256) {
                        int b2 = row >= LQ_;
                        int pix = row - b2 * LQ_;
                        int h = col >> 5, ch = col & 31;
                        valT[(((size_t)(b2 * NH_ + h) * LQ_) + pix) * 32 + ch] = f2b(v);
                    } else {
                        out[(size_t)row * NQ2 + (col - 256)] = f2b(v);
                    }
                } else {
                    float t = 0.5f * v * (1.0f + erff(v * 0.70710678f));
                    out[(size_t)row * Ndim + col] = f2b(t);
                }
            }
        }
    }
}

// ------------- fused w_out GEMM + residual + LN4 ----------------------------
__launch_bounds__(256, 2)
__global__ void gemm_wout_ln(const u16* __restrict__ A, const u16* __restrict__ Bt,
                             const float* __restrict__ bias, const float* __restrict__ res,
                             const float* __restrict__ g4, const float* __restrict__ b4,
                             float* __restrict__ x2, u16* __restrict__ hb) {
    __shared__ __align__(16) u16 lsA[32 * BK];
    __shared__ __align__(16) u16 lsB[256 * BK];   // reused as f32 tile [32][256]
    int m0 = blockIdx.x * 32;
    int tid = threadIdx.x;
    int lane = tid & 63, wv = tid >> 6;
    int quad = lane >> 4, l16 = lane & 15;
    int r0 = (wv & 1) * 16, c0 = (wv >> 1) * 128;

    f32x4 acc[8];
#pragma unroll
    for (int j = 0; j < 8; j++) { f32x4 z = {0.f, 0.f, 0.f, 0.f}; acc[j] = z; }

    for (int k0 = 0; k0 < 256; k0 += BK) {
        __syncthreads();
        {
            int cc = wv * 64 + lane;
            int row = cc >> 3, kc = (cc & 7) << 3;
            gload16(A + (size_t)(m0 + row) * 256 + k0 + kc, &lsA[(wv * 64) * 8]);
        }
#pragma unroll
        for (int s = 0; s < 8; s++) {
            int cc = s * 256 + wv * 64 + lane;
            int row = cc >> 3, kc = (cc & 7) << 3;
            gload16(Bt + (size_t)row * 256 + k0 + kc, &lsB[(s * 256 + wv * 64) * 8]);
        }
        __syncthreads();
#pragma unroll
        for (int kk = 0; kk < 2; kk++) {
            bf16x8 af, bfr[8];
            af = *(const bf16x8*)(&lsA[(r0 + l16) * BK + kk * 32 + quad * 8]);
#pragma unroll
            for (int j = 0; j < 8; j++)
                bfr[j] = *(const bf16x8*)(&lsB[(c0 + j * 16 + l16) * BK + kk * 32 + quad * 8]);
#pragma unroll
            for (int j = 0; j < 8; j++)
                acc[j] = __builtin_amdgcn_mfma_f32_16x16x32_bf16(af, bfr[j], acc[j], 0, 0, 0);
        }
    }

    __syncthreads();
    float* tile = (float*)lsB;          // [32][256]
#pragma unroll
    for (int j = 0; j < 8; j++) {
        int col = c0 + j * 16 + l16;
        float bb = bias[col];
#pragma unroll
        for (int r = 0; r < 4; r++) {
            int rl = r0 + quad * 4 + r;
            int row = m0 + rl;
            float v = acc[j][r] + bb + res[(size_t)row * C_ + col];
            tile[rl * 256 + col] = v;
            x2[(size_t)row * C_ + col] = v;
        }
    }
    __syncthreads();
    const float4 gg = *(const float4*)(g4 + lane * 4);
    const float4 bv = *(const float4*)(b4 + lane * 4);
#pragma unroll
    for (int rr = 0; rr < 8; rr++) {
        int rl = wv * 8 + rr;
        float4 v = *(const float4*)(&tile[rl * 256 + lane * 4]);
        float s = v.x + v.y + v.z + v.w;
        float s2 = v.x * v.x + v.y * v.y + v.z * v.z + v.w * v.w;
#pragma unroll
        for (int o = 1; o < 64; o <<= 1) {
            s  += __shfl_xor(s, o, 64);
            s2 += __shfl_xor(s2, o, 64);
        }
        float mean = s * (1.0f / C_);
        float var = s2 * (1.0f / C_) - mean * mean;
        float rstd = rsqrtf(var + 1e-5f);
        unsigned lo = (unsigned)f2b((v.x - mean) * rstd * gg.x + bv.x) |
                      ((unsigned)f2b((v.y - mean) * rstd * gg.y + bv.y) << 16);
        unsigned hi = (unsigned)f2b((v.z - mean) * rstd * gg.z + bv.z) |
                      ((unsigned)f2b((v.w - mean) * rstd * gg.w + bv.w) << 16);
        uint2 pk = { lo, hi };
        *(uint2*)(hb + (size_t)(m0 + rl) * C_ + lane * 4) = pk;
    }
}

// ------------- bf16 MFMA GEMM, 64x128 tile, BK=64, residual epilogue --------
__launch_bounds__(256, 4)
__global__ void gemm64_res(const u16* __restrict__ A, const u16* __restrict__ Bt,
                           const float* __restrict__ bias, const float* __restrict__ res,
                           float* __restrict__ out, int Mdim, int Ndim, int Kdim,
                           int nTiles) {
    __shared__ __align__(16) u16 lsA[64 * BK];
    __shared__ __align__(16) u16 lsB[128 * BK];
    int bm = blockIdx.x / nTiles, bn = blockIdx.x % nTiles;
    int m0 = bm * 64, n0 = bn * 128;
    int tid = threadIdx.x;
    int lane = tid & 63, wv = tid >> 6;
    int quad = lane >> 4, l16 = lane & 15;
    int rw = wv * 16;

    f32x4 acc[8];
#pragma unroll
    for (int j = 0; j < 8; j++) { f32x4 z = {0.f, 0.f, 0.f, 0.f}; acc[j] = z; }

    for (int k0 = 0; k0 < Kdim; k0 += BK) {
        __syncthreads();
#pragma unroll
        for (int s = 0; s < 2; s++) {
            int cc = s * 256 + wv * 64 + lane;
            int row = cc >> 3, kc = (cc & 7) << 3;
            gload16(A + (size_t)(m0 + row) * Kdim + k0 + kc, &lsA[(s * 256 + wv * 64) * 8]);
        }
#pragma unroll
        for (int s = 0; s < 4; s++) {
            int cc = s * 256 + wv * 64 + lane;
            int row = cc >> 3, kc = (cc & 7) << 3;
            gload16(Bt + (size_t)(n0 + row) * Kdim + k0 + kc, &lsB[(s * 256 + wv * 64) * 8]);
        }
        __syncthreads();
#pragma unroll
        for (int kk = 0; kk < 2; kk++) {
            bf16x8 af, bfr[8];
            af = *(const bf16x8*)(&lsA[(rw + l16) * BK + kk * 32 + quad * 8]);
#pragma unroll
            for (int j = 0; j < 8; j++)
                bfr[j] = *(const bf16x8*)(&lsB[(j * 16 + l16) * BK + kk * 32 + quad * 8]);
#pragma unroll
            for (int j = 0; j < 8; j++)
                acc[j] = __builtin_amdgcn_mfma_f32_16x16x32_bf16(af, bfr[j], acc[j], 0, 0, 0);
        }
    }

#pragma unroll
    for (int j = 0; j < 8; j++) {
        int col = n0 + j * 16 + l16;
        float bb = bias[col];
#pragma unroll
        for (int r = 0; r < 4; r++) {
            int row = m0 + rw + quad * 4 + r;
            size_t off = (size_t)row * Ndim + col;
            out[off] = acc[j][r] + bb + res[off];
        }
    }
}

// ------------- MSDeformAttn sampling (R8 gather, split 4-way) ---------------
// Split by (batch, head-half) into 4 dispatches: 5120 blocks x 128 threads
// (4 head-groups of 32 lanes). Identical per-thread work to R8; LDS halves
// to 10.75KB. Diagnostic: each quarter ~20us so the next-slowest kernel
// surfaces in top-5 rocprof.
#define SPC 84
__launch_bounds__(128, 2)
__global__ void msdeform_sample(const u16* __restrict__ qkv2,
                                const u16* __restrict__ valT,
                                const float* __restrict__ ref,
                                u16* __restrict__ outp,
                                int g0, int m0base) {
    __shared__ int2 sparam[4 * 4 * SPC];   // [localhead][corner][sample]
    int m = m0base + blockIdx.x;
    int b = m / LQ_;
    int tid = threadIdx.x;
    int g = tid >> 5;          // local head 0..3
    int gh = g0 + g;           // global head
    int lane = tid & 31;

    const u16* logit_base = qkv2 + (size_t)m * NQ2 + 1280 + gh * 80;
    const u16* off_base   = qkv2 + (size_t)m * NQ2 + gh * 160;

    // softmax over 80 (lanes handle i, i+32, i+64)
    float lv[3];
    float lmax = -1e30f;
    {
        int c = 0;
        for (int i = lane; i < 80; i += 32, c++) {
            lv[c] = b2f(logit_base[i]);
            lmax = fmaxf(lmax, lv[c]);
        }
    }
#pragma unroll
    for (int o = 16; o > 0; o >>= 1) lmax = fmaxf(lmax, __shfl_xor(lmax, o, 32));
    float lsum = 0.f;
    {
        int c = 0;
        for (int i = lane; i < 80; i += 32, c++) {
            lv[c] = __expf(lv[c] - lmax);
            lsum += lv[c];
        }
    }
#pragma unroll
    for (int o = 16; o > 0; o >>= 1) lsum += __shfl_xor(lsum, o, 32);
    float inv = 1.0f / lsum;

    // per-(sample,corner) params -> LDS
    {
        int c = 0;
        for (int i = lane; i < 80; i += 32, c++) {
            float aw = lv[c] * inv;
            int l = i >> 4, p = i & 15;
            float rx = ref[((size_t)m * NL_ + l) * 2 + 0];
            float ry = ref[((size_t)m * NL_ + l) * 2 + 1];
            float ox = b2f(off_base[l * 32 + p * 2 + 0]);
            float oy = b2f(off_base[l * 32 + p * 2 + 1]);
            float px = rx * (float)W_ + ox - 0.5f;
            float py = ry * (float)H_ + oy - 0.5f;
            float x0 = floorf(px), y0 = floorf(py);
            float fx = px - x0, fy = py - y0;
            int x0i = (int)x0, y0i = (int)y0;
            int hbase = (b * NH_ + gh) * LQ_ + l * HW_;
            int sbase = g * 4 * SPC + i;
#pragma unroll
            for (int cc = 0; cc < 4; cc++) {
                int dy = cc >> 1, dx = cc & 1;
                int xi = x0i + dx, yi = y0i + dy;
                float wgt = (dy ? fy : 1.f - fy) * (dx ? fx : 1.f - fx);
                bool valid = (xi >= 0) && (xi < W_) && (yi >= 0) && (yi < H_);
                int xc = min(max(xi, 0), W_ - 1);
                int yc = min(max(yi, 0), H_ - 1);
                int boff = (hbase + yc * W_ + xc) * 64;   // bytes into valT
                float w = valid ? wgt * aw : 0.f;
                int2 pk = { boff, __float_as_int(w) };
                sparam[sbase + cc * SPC] = pk;
            }
        }
    }
    __syncthreads();

    // gather: corner c = lane>>3, parity s2 = (lane>>2)&1, chquad = lane&3
    const char* qb = (const char*)valT;
    int c4 = lane >> 3;
    int s2 = (lane >> 2) & 1;
    int chq = lane & 3;
    int pbase = g * 4 * SPC + c4 * SPC + s2;
    int laneoff = chq * 16;                 // 8 channels * 2 bytes
    float a0 = 0.f, a1 = 0.f, a2 = 0.f, a3 = 0.f;
    float a4 = 0.f, a5 = 0.f, a6 = 0.f, a7 = 0.f;
    for (int ii = 0; ii < 40; ii += 8) {
        int2 pp[8];
        uint4 vv[8];
#pragma unroll
        for (int j = 0; j < 8; j++) pp[j] = sparam[pbase + (ii + j) * 2];
#pragma unroll
        for (int j = 0; j < 8; j++) vv[j] = *(const uint4*)(qb + pp[j].x + laneoff);
#pragma unroll
        for (int j = 0; j < 8; j++) {
            float w = __int_as_float(pp[j].y);
            uint4 v = vv[j];
            union { unsigned u; float f; } t;
            t.u = v.x << 16;         a0 += w * t.f;
            t.u = v.x & 0xffff0000u; a1 += w * t.f;
            t.u = v.y << 16;         a2 += w * t.f;
            t.u = v.y & 0xffff0000u; a3 += w * t.f;
            t.u = v.z << 16;         a4 += w * t.f;
            t.u = v.z & 0xffff0000u; a5 += w * t.f;
            t.u = v.w << 16;         a6 += w * t.f;
            t.u = v.w & 0xffff0000u; a7 += w * t.f;
        }
    }
    // reduce parity (xor 4) then corners (xor 8, 16)
#pragma unroll
    for (int o = 4; o <= 16; o <<= 1) {
        a0 += __shfl_xor(a0, o, 32); a1 += __shfl_xor(a1, o, 32);
        a2 += __shfl_xor(a2, o, 32); a3 += __shfl_xor(a3, o, 32);
        a4 += __shfl_xor(a4, o, 32); a5 += __shfl_xor(a5, o, 32);
        a6 += __shfl_xor(a6, o, 32); a7 += __shfl_xor(a7, o, 32);
    }
    if (lane < 4) {
        uint4 pk;
        pk.x = (unsigned)f2b(a0) | ((unsigned)f2b(a1) << 16);
        pk.y = (unsigned)f2b(a2) | ((unsigned)f2b(a3) << 16);
        pk.z = (unsigned)f2b(a4) | ((unsigned)f2b(a5) << 16);
        pk.w = (unsigned)f2b(a6) | ((unsigned)f2b(a7) << 16);
        *(uint4*)(outp + (size_t)m * C_ + gh * 32 + chq * 8) = pk;
    }
}

// ---------------------------------------------------------------------------
extern "C" void kernel_launch(void* const* d_in, const int* in_sizes, int n_in,
                              void* d_out, int out_size, void* d_ws, size_t ws_size,
                              hipStream_t stream) {
    const float* x      = (const float*)d_in[0];
    const float* ref    = (const float*)d_in[1];
    const float* n3g    = (const float*)d_in[4];
    const float* n3b    = (const float*)d_in[5];
    const float* n4g    = (const float*)d_in[6];
    const float* n4b    = (const float*)d_in[7];
    const float* w_off  = (const float*)d_in[8];
    const float* b_off  = (const float*)d_in[9];
    const float* w_attn = (const float*)d_in[10];
    const float* b_attn = (const float*)d_in[11];
    const float* w_val  = (const float*)d_in[12];
    const float* b_val  = (const float*)d_in[13];
    const float* w_out  = (const float*)d_in[14];
    const float* b_out  = (const float*)d_in[15];
    const float* w_fc1  = (const float*)d_in[16];
    const float* b_fc1  = (const float*)d_in[17];
    const float* w_fc2  = (const float*)d_in[18];
    const float* b_fc2  = (const float*)d_in[19];
    float* out = (float*)d_out;

    // workspace layout
    u16*   wcatT   = (u16*)d_ws;                       // bf16 [2176][256]
    float* biascat = (float*)(wcatT + (size_t)NCAT * 256); // f32 [2176] (pad 2304)
    u16*   woutT   = (u16*)(biascat + 2304);           // bf16 [256][256]
    u16*   wfc1T   = woutT + 256 * 256;                // bf16 [1024][256]
    u16*   wfc2T   = wfc1T + 1024 * 256;               // bf16 [256][1024]
    u16*   qbuf    = wfc2T + 256 * 1024;               // bf16 [M][256]
    u16*   valT    = qbuf + (size_t)M_ * 256;          // bf16 [B][NH][LQ][32]
    u16*   qkv2    = valT + (size_t)M_ * 256;          // bf16 [M][1920]
    u16*   outp    = qkv2 + (size_t)M_ * NQ2;          // bf16 [M][256]
    // overlay on qkv2 after sampling:
    float* x2      = (float*)qkv2;                     // f32 [M][256]
    u16*   hbuf    = (u16*)(x2 + (size_t)M_ * 256);    // bf16 [M][256]
    u16*   gbuf    = hbuf + (size_t)M_ * 256;          // bf16 [M][1024]

    // 1) weight prep + LN3 fused (independent work, one dispatch)
    prep_and_ln3<<<dim3(PREP_BLKS + M_ / 4), dim3(256), 0, stream>>>(
        w_val, w_off, w_attn, w_out, w_fc1, w_fc2, b_val, b_off, b_attn,
        wcatT, woutT, wfc1T, wfc2T, biascat, x, n3g, n3b, qbuf);

    // 2) fused val/off/attn GEMM -> valT (head-major) + qkv2 (off|logits)
    gemm128<<<dim3(80 * 17), dim3(256), 0, stream>>>(
        qbuf, wcatT, biascat, qkv2, valT, M_, NCAT, 256, 0, 17);

    // 3) deformable sampling -> outp (bf16 [M,256]) — split 4-way (diagnostic)
    msdeform_sample<<<dim3(LQ_), dim3(128), 0, stream>>>(qkv2, valT, ref, outp, 0, 0);
    msdeform_sample<<<dim3(LQ_), dim3(128), 0, stream>>>(qkv2, valT, ref, outp, 4, 0);
    msdeform_sample<<<dim3(LQ_), dim3(128), 0, stream>>>(qkv2, valT, ref, outp, 0, LQ_);
    msdeform_sample<<<dim3(LQ_), dim3(128), 0, stream>>>(qkv2, valT, ref, outp, 4, LQ_);

    // 4) fused w_out GEMM + residual x + LN4 -> x2 (f32), hbuf (bf16)
    gemm_wout_ln<<<dim3(M_ / 32), dim3(256), 0, stream>>>(
        outp, woutT, b_out, x, n4g, n4b, x2, hbuf);

    // 5) fc1 GEMM + exact GELU -> gbuf (bf16 [M,1024])
    gemm128<<<dim3(80 * 8), dim3(256), 0, stream>>>(
        hbuf, wfc1T, b_fc1, gbuf, nullptr, M_, 1024, 256, 1, 8);

    // 6) fc2 GEMM + residual x2 -> d_out (f32)
    gemm64_res<<<dim3(160 * 2), dim3(256), 0, stream>>>(
        gbuf, wfc2T, b_fc2, x2, out, M_, 256, 1024, 2);
}

// Round 10
// 258.588 us; speedup vs baseline: 1.0585x; 1.0585x over previous
//
#include <hip/hip_runtime.h>
#include <hip/hip_bf16.h>
#include <math.h>

#define B_   2
#define D_   5
#define H_   32
#define W_   32
#define C_   256
#define NH_  8
#define NL_  5
#define NP_  16
#define HD_  32
#define HW_  1024
#define LQ_  5120            // D*H*W
#define M_   (B_*LQ_)        // 10240 rows
#define MLP_ 1024
#define NCAT 2176            // GEMM N: 256 val + 1280 off + 640 logits
#define NQ2  1920            // compact qkv2 row: 1280 off + 640 logits

typedef unsigned short u16;
typedef __bf16 bf16x8 __attribute__((ext_vector_type(8)));
typedef float  f32x4  __attribute__((ext_vector_type(4)));

__device__ __forceinline__ float b2f(u16 v) {
    union { float f; unsigned u; } x; x.u = ((unsigned)v) << 16; return x.f;
}
__device__ __forceinline__ u16 f2b(float f) {
    union { float f; unsigned u; } x; x.f = f;
    unsigned r = x.u + 0x7fffu + ((x.u >> 16) & 1u);
    return (u16)(r >> 16);
}
__device__ __forceinline__ void gload16(const u16* g, u16* l) {
    __builtin_amdgcn_global_load_lds(
        (const __attribute__((address_space(1))) unsigned int*)g,
        (__attribute__((address_space(3))) unsigned int*)l, 16, 0, 0);
}

// ------------- weight prep + LN3 fused in ONE dispatch ----------------------
#define SEG0 557056
#define SEG1 622592
#define SEG2 884736
#define SEG3 1146880
#define SEGT 1149056
#define PREP_BLKS ((SEGT + 255) / 256)
__global__ void prep_and_ln3(const float* __restrict__ w_val, const float* __restrict__ w_off,
                             const float* __restrict__ w_attn, const float* __restrict__ w_out,
                             const float* __restrict__ w_fc1, const float* __restrict__ w_fc2,
                             const float* __restrict__ b_val, const float* __restrict__ b_off,
                             const float* __restrict__ b_attn,
                             u16* __restrict__ wcatT, u16* __restrict__ woutT,
                             u16* __restrict__ wfc1T, u16* __restrict__ wfc2T,
                             float* __restrict__ biascat,
                             const float* __restrict__ x, const float* __restrict__ g3,
                             const float* __restrict__ b3, u16* __restrict__ qbuf) {
    if (blockIdx.x >= PREP_BLKS) {
        // ---- LN3: one wave per row, 4 rows/block ----
        int wave = threadIdx.x >> 6, lane = threadIdx.x & 63;
        int row = (blockIdx.x - PREP_BLKS) * 4 + wave;
        const float4 v = *(const float4*)(x + (size_t)row * C_ + lane * 4);
        float s = v.x + v.y + v.z + v.w;
#pragma unroll
        for (int o = 1; o < 64; o <<= 1) s += __shfl_xor(s, o, 64);
        float mean = s * (1.0f / C_);
        float4 d = { v.x - mean, v.y - mean, v.z - mean, v.w - mean };
        float s2 = d.x * d.x + d.y * d.y + d.z * d.z + d.w * d.w;
#pragma unroll
        for (int o = 1; o < 64; o <<= 1) s2 += __shfl_xor(s2, o, 64);
        float r = rsqrtf(s2 * (1.0f / C_) + 1e-5f);
        const float4 gg = *(const float4*)(g3 + lane * 4);
        const float4 bb = *(const float4*)(b3 + lane * 4);
        unsigned lo = (unsigned)f2b(d.x * r * gg.x + bb.x) |
                      ((unsigned)f2b(d.y * r * gg.y + bb.y) << 16);
        unsigned hi = (unsigned)f2b(d.z * r * gg.z + bb.z) |
                      ((unsigned)f2b(d.w * r * gg.w + bb.w) << 16);
        uint2 pk = { lo, hi };
        *(uint2*)(qbuf + (size_t)row * C_ + lane * 4) = pk;
        return;
    }
    int idx = blockIdx.x * blockDim.x + threadIdx.x;
    if (idx < SEG0) {
        int n = idx >> 8, k = idx & 255;
        float v;
        if (n < 256)        v = w_val[k * 256 + n];
        else if (n < 1536)  v = w_off[k * 1280 + (n - 256)];
        else                v = w_attn[k * 640 + (n - 1536)];
        wcatT[idx] = f2b(v);
    } else if (idx < SEG1) {
        int i = idx - SEG0; int n = i >> 8, k = i & 255;
        woutT[i] = f2b(w_out[k * 256 + n]);
    } else if (idx < SEG2) {
        int i = idx - SEG1; int n = i >> 8, k = i & 255;
        wfc1T[i] = f2b(w_fc1[k * 1024 + n]);
    } else if (idx < SEG3) {
        int i = idx - SEG2; int n = i >> 10, k = i & 1023;
        wfc2T[i] = f2b(w_fc2[k * 256 + n]);
    } else if (idx < SEGT) {
        int t = idx - SEG3;
        float v;
        if (t < 256)        v = b_val[t];
        else if (t < 1536)  v = b_off[t - 256];
        else                v = b_attn[t - 1536];
        biascat[t] = v;
    }
}

// ------------- bf16 MFMA GEMM, 128x128 tile, BK=64, global_load_lds ---------
// mode 0: qkv split — col<256 scatter to valT[b][h][pix][32], else qkv2[M][1920]
// mode 1: out bf16 = gelu (tanh form, ~1e-3 of exact)
#define BK 64
__launch_bounds__(256, 2)
__global__ void gemm128(const u16* __restrict__ A, const u16* __restrict__ Bt,
                        const float* __restrict__ bias,
                        u16* __restrict__ out, u16* __restrict__ valT,
                        int Mdim, int Ndim, int Kdim,
                        int mode, int nTiles) {
    __shared__ __align__(16) u16 lsA[128 * BK];
    __shared__ __align__(16) u16 lsB[128 * BK];
    int bm = blockIdx.x / nTiles, bn = blockIdx.x % nTiles;
    int m0 = bm * 128, n0 = bn * 128;
    int tid = threadIdx.x;
    int lane = tid & 63, wv = tid >> 6;
    int quad = lane >> 4, l16 = lane & 15;
    int rw = (wv >> 1) * 64, cw = (wv & 1) * 64;

    f32x4 acc[4][4];
#pragma unroll
    for (int i = 0; i < 4; i++)
#pragma unroll
        for (int j = 0; j < 4; j++) { f32x4 z = {0.f, 0.f, 0.f, 0.f}; acc[i][j] = z; }

    for (int k0 = 0; k0 < Kdim; k0 += BK) {
        __syncthreads();
#pragma unroll
        for (int s = 0; s < 4; s++) {
            int cc = s * 256 + wv * 64 + lane;
            int row = cc >> 3, kc = (cc & 7) << 3;
            int lbase = (s * 256 + wv * 64) * 8;   // u16 units, wave-uniform
            gload16(A  + (size_t)(m0 + row) * Kdim + k0 + kc, &lsA[lbase]);
            gload16(Bt + (size_t)(n0 + row) * Kdim + k0 + kc, &lsB[lbase]);
        }
        __syncthreads();
#pragma unroll
        for (int kk = 0; kk < 2; kk++) {
            bf16x8 af[4], bfr[4];
#pragma unroll
            for (int i = 0; i < 4; i++)
                af[i] = *(const bf16x8*)(&lsA[(rw + i * 16 + l16) * BK + kk * 32 + quad * 8]);
#pragma unroll
            for (int j = 0; j < 4; j++)
                bfr[j] = *(const bf16x8*)(&lsB[(cw + j * 16 + l16) * BK + kk * 32 + quad * 8]);
#pragma unroll
            for (int i = 0; i < 4; i++)
#pragma unroll
                for (int j = 0; j < 4; j++)
                    acc[i][j] = __builtin_amdgcn_mfma_f32_16x16x32_bf16(
                        af[i], bfr[j], acc[i][j], 0, 0, 0);
        }
    }

#pragma unroll
    for (int i = 0; i < 4; i++) {
#pragma unroll
        for (int j = 0; j < 4; j++) {
            int col = n0 + cw + j * 16 + l16;
            float bb = bias[col];
#pragma unroll
            for (int r = 0; r < 4; r++) {
                int row = m0 + rw + i * 16 + quad * 4 + r;
                float v = acc[i][j][r] + bb;
                if (mode == 0) {
                    if (col < 256) {
                        int b2 = row >= LQ_;
                        int pix = row - b2 * LQ_;
                        int h = col >> 5, ch = col & 31;
                        valT[(((size_t)(b2 * NH_ + h) * LQ_) + pix) * 32 + ch] = f2b(v);
                    } else {
                        out[(size_t)row * NQ2 + (col - 256)] = f2b(v);
                    }
                } else {
                    // gelu(v) = v - v/(exp(2u)+1), u = 0.79788456*(v+0.044715*v^3)
                    float u2 = v * (1.5957691216f + 0.0713548162f * v * v);
                    float t = v - v / (__expf(u2) + 1.0f);
                    out[(size_t)row * Ndim + col] = f2b(t);
                }
            }
        }
    }
}

// ------------- fused w_out GEMM + residual + LN4 ----------------------------
__launch_bounds__(256, 2)
__global__ void gemm_wout_ln(const u16* __restrict__ A, const u16* __restrict__ Bt,
                             const float* __restrict__ bias, const float* __restrict__ res,
                             const float* __restrict__ g4, const float* __restrict__ b4,
                             float* __restrict__ x2, u16* __restrict__ hb) {
    __shared__ __align__(16) u16 lsA[32 * BK];
    __shared__ __align__(16) u16 lsB[256 * BK];   // reused as f32 tile [32][256]
    int m0 = blockIdx.x * 32;
    int tid = threadIdx.x;
    int lane = tid & 63, wv = tid >> 6;
    int quad = lane >> 4, l16 = lane & 15;
    int r0 = (wv & 1) * 16, c0 = (wv >> 1) * 128;

    f32x4 acc[8];
#pragma unroll
    for (int j = 0; j < 8; j++) { f32x4 z = {0.f, 0.f, 0.f, 0.f}; acc[j] = z; }

    for (int k0 = 0; k0 < 256; k0 += BK) {
        __syncthreads();
        {
            int cc = wv * 64 + lane;
            int row = cc >> 3, kc = (cc & 7) << 3;
            gload16(A + (size_t)(m0 + row) * 256 + k0 + kc, &lsA[(wv * 64) * 8]);
        }
#pragma unroll
        for (int s = 0; s < 8; s++) {
            int cc = s * 256 + wv * 64 + lane;
            int row = cc >> 3, kc = (cc & 7) << 3;
            gload16(Bt + (size_t)row * 256 + k0 + kc, &lsB[(s * 256 + wv * 64) * 8]);
        }
        __syncthreads();
#pragma unroll
        for (int kk = 0; kk < 2; kk++) {
            bf16x8 af, bfr[8];
            af = *(const bf16x8*)(&lsA[(r0 + l16) * BK + kk * 32 + quad * 8]);
#pragma unroll
            for (int j = 0; j < 8; j++)
                bfr[j] = *(const bf16x8*)(&lsB[(c0 + j * 16 + l16) * BK + kk * 32 + quad * 8]);
#pragma unroll
            for (int j = 0; j < 8; j++)
                acc[j] = __builtin_amdgcn_mfma_f32_16x16x32_bf16(af, bfr[j], acc[j], 0, 0, 0);
        }
    }

    __syncthreads();
    float* tile = (float*)lsB;          // [32][256]
#pragma unroll
    for (int j = 0; j < 8; j++) {
        int col = c0 + j * 16 + l16;
        float bb = bias[col];
#pragma unroll
        for (int r = 0; r < 4; r++) {
            int rl = r0 + quad * 4 + r;
            int row = m0 + rl;
            float v = acc[j][r] + bb + res[(size_t)row * C_ + col];
            tile[rl * 256 + col] = v;
            x2[(size_t)row * C_ + col] = v;
        }
    }
    __syncthreads();
    const float4 gg = *(const float4*)(g4 + lane * 4);
    const float4 bv = *(const float4*)(b4 + lane * 4);
#pragma unroll
    for (int rr = 0; rr < 8; rr++) {
        int rl = wv * 8 + rr;
        float4 v = *(const float4*)(&tile[rl * 256 + lane * 4]);
        float s = v.x + v.y + v.z + v.w;
        float s2 = v.x * v.x + v.y * v.y + v.z * v.z + v.w * v.w;
#pragma unroll
        for (int o = 1; o < 64; o <<= 1) {
            s  += __shfl_xor(s, o, 64);
            s2 += __shfl_xor(s2, o, 64);
        }
        float mean = s * (1.0f / C_);
        float var = s2 * (1.0f / C_) - mean * mean;
        float rstd = rsqrtf(var + 1e-5f);
        unsigned lo = (unsigned)f2b((v.x - mean) * rstd * gg.x + bv.x) |
                      ((unsigned)f2b((v.y - mean) * rstd * gg.y + bv.y) << 16);
        unsigned hi = (unsigned)f2b((v.z - mean) * rstd * gg.z + bv.z) |
                      ((unsigned)f2b((v.w - mean) * rstd * gg.w + bv.w) << 16);
        uint2 pk = { lo, hi };
        *(uint2*)(hb + (size_t)(m0 + rl) * C_ + lane * 4) = pk;
    }
}

// ------------- bf16 MFMA GEMM, 64x128 tile, BK=64, residual epilogue --------
__launch_bounds__(256, 4)
__global__ void gemm64_res(const u16* __restrict__ A, const u16* __restrict__ Bt,
                           const float* __restrict__ bias, const float* __restrict__ res,
                           float* __restrict__ out, int Mdim, int Ndim, int Kdim,
                           int nTiles) {
    __shared__ __align__(16) u16 lsA[64 * BK];
    __shared__ __align__(16) u16 lsB[128 * BK];
    int bm = blockIdx.x / nTiles, bn = blockIdx.x % nTiles;
    int m0 = bm * 64, n0 = bn * 128;
    int tid = threadIdx.x;
    int lane = tid & 63, wv = tid >> 6;
    int quad = lane >> 4, l16 = lane & 15;
    int rw = wv * 16;

    f32x4 acc[8];
#pragma unroll
    for (int j = 0; j < 8; j++) { f32x4 z = {0.f, 0.f, 0.f, 0.f}; acc[j] = z; }

    for (int k0 = 0; k0 < Kdim; k0 += BK) {
        __syncthreads();
#pragma unroll
        for (int s = 0; s < 2; s++) {
            int cc = s * 256 + wv * 64 + lane;
            int row = cc >> 3, kc = (cc & 7) << 3;
            gload16(A + (size_t)(m0 + row) * Kdim + k0 + kc, &lsA[(s * 256 + wv * 64) * 8]);
        }
#pragma unroll
        for (int s = 0; s < 4; s++) {
            int cc = s * 256 + wv * 64 + lane;
            int row = cc >> 3, kc = (cc & 7) << 3;
            gload16(Bt + (size_t)(n0 + row) * Kdim + k0 + kc, &lsB[(s * 256 + wv * 64) * 8]);
        }
        __syncthreads();
#pragma unroll
        for (int kk = 0; kk < 2; kk++) {
            bf16x8 af, bfr[8];
            af = *(const bf16x8*)(&lsA[(rw + l16) * BK + kk * 32 + quad * 8]);
#pragma unroll
            for (int j = 0; j < 8; j++)
                bfr[j] = *(const bf16x8*)(&lsB[(j * 16 + l16) * BK + kk * 32 + quad * 8]);
#pragma unroll
            for (int j = 0; j < 8; j++)
                acc[j] = __builtin_amdgcn_mfma_f32_16x16x32_bf16(af, bfr[j], acc[j], 0, 0, 0);
        }
    }

#pragma unroll
    for (int j = 0; j < 8; j++) {
        int col = n0 + j * 16 + l16;
        float bb = bias[col];
#pragma unroll
        for (int r = 0; r < 4; r++) {
            int row = m0 + rw + quad * 4 + r;
            size_t off = (size_t)row * Ndim + col;
            out[off] = acc[j][r] + bb + res[off];
        }
    }
}

// ------------- MSDeformAttn sampling (R8 gather, occupancy 4 blk/CU) --------
// qkv2 row m (bf16 [M][1920]): [0,1280) off, [1280,1920) logits.
// valT bf16 [B][NH][LQ][32] — pixel stride 64 B per head.
// 1 block per (b,q); 8 groups of 32 lanes, one head each.
// Gather: lane = corner(2b) | parity(1b) | chquad(2b); dwordx4 = 8 channels.
// launch_bounds(256,4): VGPR<=128, LDS 21.5KB*4=86KB<160KB -> 4 blocks/CU
// (R8 ran at 57% occupancy; this probes whether the 1.9x-over-line-floor gap
// has a latency component).
#define SPC 84
__launch_bounds__(256, 4)
__global__ void msdeform_sample(const u16* __restrict__ qkv2,
                                const u16* __restrict__ valT,
                                const float* __restrict__ ref,
                                u16* __restrict__ outp) {
    __shared__ int2 sparam[NH_ * 4 * SPC];   // [head][corner][sample] {byteoff, w}
    int m = blockIdx.x;
    int b = m / LQ_;
    int tid = threadIdx.x;
    int g = tid >> 5;          // head
    int lane = tid & 31;

    const u16* logit_base = qkv2 + (size_t)m * NQ2 + 1280 + g * 80;
    const u16* off_base   = qkv2 + (size_t)m * NQ2 + g * 160;

    // softmax over 80 (lanes handle i, i+32, i+64)
    float lv[3];
    float lmax = -1e30f;
    {
        int c = 0;
        for (int i = lane; i < 80; i += 32, c++) {
            lv[c] = b2f(logit_base[i]);
            lmax = fmaxf(lmax, lv[c]);
        }
    }
#pragma unroll
    for (int o = 16; o > 0; o >>= 1) lmax = fmaxf(lmax, __shfl_xor(lmax, o, 32));
    float lsum = 0.f;
    {
        int c = 0;
        for (int i = lane; i < 80; i += 32, c++) {
            lv[c] = __expf(lv[c] - lmax);
            lsum += lv[c];
        }
    }
#pragma unroll
    for (int o = 16; o > 0; o >>= 1) lsum += __shfl_xor(lsum, o, 32);
    float inv = 1.0f / lsum;

    // per-(sample,corner) params -> LDS
    {
        int c = 0;
        for (int i = lane; i < 80; i += 32, c++) {
            float aw = lv[c] * inv;
            int l = i >> 4, p = i & 15;
            float rx = ref[((size_t)m * NL_ + l) * 2 + 0];
            float ry = ref[((size_t)m * NL_ + l) * 2 + 1];
            float ox = b2f(off_base[l * 32 + p * 2 + 0]);
            float oy = b2f(off_base[l * 32 + p * 2 + 1]);
            float px = rx * (float)W_ + ox - 0.5f;
            float py = ry * (float)H_ + oy - 0.5f;
            float x0 = floorf(px), y0 = floorf(py);
            float fx = px - x0, fy = py - y0;
            int x0i = (int)x0, y0i = (int)y0;
            int hbase = (b * NH_ + g) * LQ_ + l * HW_;
            int sbase = g * 4 * SPC + i;
#pragma unroll
            for (int cc = 0; cc < 4; cc++) {
                int dy = cc >> 1, dx = cc & 1;
                int xi = x0i + dx, yi = y0i + dy;
                float wgt = (dy ? fy : 1.f - fy) * (dx ? fx : 1.f - fx);
                bool valid = (xi >= 0) && (xi < W_) && (yi >= 0) && (yi < H_);
                int xc = min(max(xi, 0), W_ - 1);
                int yc = min(max(yi, 0), H_ - 1);
                int boff = (hbase + yc * W_ + xc) * 64;   // bytes into valT
                float w = valid ? wgt * aw : 0.f;
                int2 pk = { boff, __float_as_int(w) };
                sparam[sbase + cc * SPC] = pk;
            }
        }
    }
    __syncthreads();

    // gather: corner c = lane>>3, parity s2 = (lane>>2)&1, chquad = lane&3
    const char* qb = (const char*)valT;
    int c4 = lane >> 3;
    int s2 = (lane >> 2) & 1;
    int chq = lane & 3;
    int pbase = g * 4 * SPC + c4 * SPC + s2;
    int laneoff = chq * 16;                 // 8 channels * 2 bytes
    float a0 = 0.f, a1 = 0.f, a2 = 0.f, a3 = 0.f;
    float a4 = 0.f, a5 = 0.f, a6 = 0.f, a7 = 0.f;
    for (int ii = 0; ii < 40; ii += 8) {
        int2 pp[8];
        uint4 vv[8];
#pragma unroll
        for (int j = 0; j < 8; j++) pp[j] = sparam[pbase + (ii + j) * 2];
#pragma unroll
        for (int j = 0; j < 8; j++) vv[j] = *(const uint4*)(qb + pp[j].x + laneoff);
#pragma unroll
        for (int j = 0; j < 8; j++) {
            float w = __int_as_float(pp[j].y);
            uint4 v = vv[j];
            union { unsigned u; float f; } t;
            t.u = v.x << 16;         a0 += w * t.f;
            t.u = v.x & 0xffff0000u; a1 += w * t.f;
            t.u = v.y << 16;         a2 += w * t.f;
            t.u = v.y & 0xffff0000u; a3 += w * t.f;
            t.u = v.z << 16;         a4 += w * t.f;
            t.u = v.z & 0xffff0000u; a5 += w * t.f;
            t.u = v.w << 16;         a6 += w * t.f;
            t.u = v.w & 0xffff0000u; a7 += w * t.f;
        }
    }
    // reduce parity (xor 4) then corners (xor 8, 16)
#pragma unroll
    for (int o = 4; o <= 16; o <<= 1) {
        a0 += __shfl_xor(a0, o, 32); a1 += __shfl_xor(a1, o, 32);
        a2 += __shfl_xor(a2, o, 32); a3 += __shfl_xor(a3, o, 32);
        a4 += __shfl_xor(a4, o, 32); a5 += __shfl_xor(a5, o, 32);
        a6 += __shfl_xor(a6, o, 32); a7 += __shfl_xor(a7, o, 32);
    }
    if (lane < 4) {
        uint4 pk;
        pk.x = (unsigned)f2b(a0) | ((unsigned)f2b(a1) << 16);
        pk.y = (unsigned)f2b(a2) | ((unsigned)f2b(a3) << 16);
        pk.z = (unsigned)f2b(a4) | ((unsigned)f2b(a5) << 16);
        pk.w = (unsigned)f2b(a6) | ((unsigned)f2b(a7) << 16);
        *(uint4*)(outp + (size_t)m * C_ + g * 32 + chq * 8) = pk;
    }
}

// ---------------------------------------------------------------------------
extern "C" void kernel_launch(void* const* d_in, const int* in_sizes, int n_in,
                              void* d_out, int out_size, void* d_ws, size_t ws_size,
                              hipStream_t stream) {
    const float* x      = (const float*)d_in[0];
    const float* ref    = (const float*)d_in[1];
    const float* n3g    = (const float*)d_in[4];
    const float* n3b    = (const float*)d_in[5];
    const float* n4g    = (const float*)d_in[6];
    const float* n4b    = (const float*)d_in[7];
    const float* w_off  = (const float*)d_in[8];
    const float* b_off  = (const float*)d_in[9];
    const float* w_attn = (const float*)d_in[10];
    const float* b_attn = (const float*)d_in[11];
    const float* w_val  = (const float*)d_in[12];
    const float* b_val  = (const float*)d_in[13];
    const float* w_out  = (const float*)d_in[14];
    const float* b_out  = (const float*)d_in[15];
    const float* w_fc1  = (const float*)d_in[16];
    const float* b_fc1  = (const float*)d_in[17];
    const float* w_fc2  = (const float*)d_in[18];
    const float* b_fc2  = (const float*)d_in[19];
    float* out = (float*)d_out;

    // workspace layout
    u16*   wcatT   = (u16*)d_ws;                       // bf16 [2176][256]
    float* biascat = (float*)(wcatT + (size_t)NCAT * 256); // f32 [2176] (pad 2304)
    u16*   woutT   = (u16*)(biascat + 2304);           // bf16 [256][256]
    u16*   wfc1T   = woutT + 256 * 256;                // bf16 [1024][256]
    u16*   wfc2T   = wfc1T + 1024 * 256;               // bf16 [256][1024]
    u16*   qbuf    = wfc2T + 256 * 1024;               // bf16 [M][256]
    u16*   valT    = qbuf + (size_t)M_ * 256;          // bf16 [B][NH][LQ][32]
    u16*   qkv2    = valT + (size_t)M_ * 256;          // bf16 [M][1920]
    u16*   outp    = qkv2 + (size_t)M_ * NQ2;          // bf16 [M][256]
    // overlay on qkv2 after sampling:
    float* x2      = (float*)qkv2;                     // f32 [M][256]
    u16*   hbuf    = (u16*)(x2 + (size_t)M_ * 256);    // bf16 [M][256]
    u16*   gbuf    = hbuf + (size_t)M_ * 256;          // bf16 [M][1024]

    // 1) weight prep + LN3 fused (independent work, one dispatch)
    prep_and_ln3<<<dim3(PREP_BLKS + M_ / 4), dim3(256), 0, stream>>>(
        w_val, w_off, w_attn, w_out, w_fc1, w_fc2, b_val, b_off, b_attn,
        wcatT, woutT, wfc1T, wfc2T, biascat, x, n3g, n3b, qbuf);

    // 2) fused val/off/attn GEMM -> valT (head-major) + qkv2 (off|logits)
    gemm128<<<dim3(80 * 17), dim3(256), 0, stream>>>(
        qbuf, wcatT, biascat, qkv2, valT, M_, NCAT, 256, 0, 17);

    // 3) deformable sampling -> outp (bf16 [M,256]) — single dispatch (revert)
    msdeform_sample<<<dim3(M_), dim3(256), 0, stream>>>(qkv2, valT, ref, outp);

    // 4) fused w_out GEMM + residual x + LN4 -> x2 (f32), hbuf (bf16)
    gemm_wout_ln<<<dim3(M_ / 32), dim3(256), 0, stream>>>(
        outp, woutT, b_out, x, n4g, n4b, x2, hbuf);

    // 5) fc1 GEMM + GELU -> gbuf (bf16 [M,1024])
    gemm128<<<dim3(80 * 8), dim3(256), 0, stream>>>(
        hbuf, wfc1T, b_fc1, gbuf, nullptr, M_, 1024, 256, 1, 8);

    // 6) fc2 GEMM + residual x2 -> d_out (f32)
    gemm64_res<<<dim3(160 * 2), dim3(256), 0, stream>>>(
        gbuf, wfc2T, b_fc2, x2, out, M_, 256, 1024, 2);
}